// Round 17
// baseline (97.056 us; speedup 1.0000x reference)
//
#include <hip/hip_runtime.h>
#include <hip/hip_bf16.h>
#include <hip/hip_fp16.h>
#include <stdint.h>

typedef __attribute__((ext_vector_type(8))) _Float16 f16x8;
typedef __attribute__((ext_vector_type(4))) float f32x4;
typedef __attribute__((ext_vector_type(4))) int i32x4;

#define GLD_LDS16(g, l) __builtin_amdgcn_global_load_lds( \
    (const __attribute__((address_space(1))) uint32_t*)(g), \
    (__attribute__((address_space(3))) uint32_t*)(l), 16, 0, 0)

// ---------------- W fp32 -> fp16 (into workspace), 512x2048 -------------
__global__ __launch_bounds__(256) void k_cvt_w(const float* __restrict__ W,
                                               _Float16* __restrict__ Wh) {
  int i = (blockIdx.x * 256 + threadIdx.x) * 8;  // 1048576 elems total
  float4 a = *(const float4*)(W + i);
  float4 b = *(const float4*)(W + i + 4);
  union { _Float16 h[8]; i32x4 v; } u;
  u.h[0] = (_Float16)a.x; u.h[1] = (_Float16)a.y;
  u.h[2] = (_Float16)a.z; u.h[3] = (_Float16)a.w;
  u.h[4] = (_Float16)b.x; u.h[5] = (_Float16)b.y;
  u.h[6] = (_Float16)b.z; u.h[7] = (_Float16)b.w;
  *(i32x4*)(Wh + i) = u.v;
}

__device__ inline float softplus_f(float x) {
  float e = __expf(-fabsf(x));
  return fmaxf(x, 0.f) + __logf(1.f + e);
}

// ---- fused GEMM(fp16 MFMA) + softplus-diff: PHASES x CO-RESIDENCY ----
// Tile 128x128 (N-split 4), BK=64, 32 K-steps. 256 thr = 4 waves 2Mx2N,
// wave-tile 64x64 (acc 4x4, 16 MFMA/phase; 2 phases/step = R15 schedule).
// LDS 64.5KB -> 2 blocks/CU (grid 512): barrier drains of one block are
// covered by the other block's waves (m114) -- the piece R15/R16 lacked.
// XCD grouping (R14-proven, FETCH 74MB): all 4 N-quarters of a row-tile
// land on one XCD. Swizzles/numerics proven (0 conflicts, absmax 0.0156).
// A staged in two 16-fp32 halves (one per phase, dist-2 prefetch).
// vmcnt ledger: P1-end vmcnt(8) drains B(t+1) (4 oldest), keeps A(t+2)
// (8 younger) in flight; cvt deps auto-waited by compiler (IR loads).
__global__ __launch_bounds__(256, 2) void k_main(
    const float* __restrict__ X,      // [16384][2048]
    const _Float16* __restrict__ Wh,  // [512][2048]
    const float* __restrict__ U,      // [512][2]
    const float* __restrict__ hb,     // [512]
    float* __restrict__ Dp) {         // [4][16384] partial logit-diffs
  __shared__ __align__(16) _Float16 As[2][128 * 64];  // 2 x 16 KB
  __shared__ __align__(16) _Float16 Bs[2][128 * 64];  // 2 x 16 KB
  __shared__ float sD[128];

  const int t = threadIdx.x;   // 0..255
  const int lane = t & 63;
  const int wid = t >> 6;      // 0..3
  const int wm = wid >> 1;     // 0..1 (M half)
  const int wn = wid & 1;      // 0..1 (N half)
  const int bx = blockIdx.x;
  const int rt = (bx >> 5) * 8 + (bx & 7);  // row-tile 0..127
  const int nq = (bx >> 3) & 3;             // 4 siblings: same XCD (mod 8)
  const int bm0 = rt * 128;
  const int bn0 = nq * 128;
  const int lrow = lane & 15, lq = lane >> 4;

  if (t < 128) sD[t] = 0.f;

  f32x4 acc[4][4];
#pragma unroll
  for (int m = 0; m < 4; ++m)
#pragma unroll
    for (int n = 0; n < 4; ++n) acc[m][n] = (f32x4){0.f, 0.f, 0.f, 0.f};

  // A staging: thread -> row t>>1 (0..127), k-half (t&1)*32 (32 fp32 ->
  // 4 fp16 chunks of 16B). Swizzled write: chunk c at row r -> byte
  // r*128 + ((c ^ (r&7))<<4)   (proven family; matches frag-read XOR).
  const int arow = t >> 1;
  const float* xsrc = X + (size_t)(bm0 + arow) * 2048 + (t & 1) * 32;
  const int c0 = (t & 1) * 4;
  int awc[4];
#pragma unroll
  for (int j = 0; j < 4; ++j)
    awc[j] = arow * 128 + (((c0 + j) ^ (arow & 7)) << 4);

  // B staging: wave wid covers W cols [wid*32,+32): 4 gld_lds of 1KB.
  // Pre-swizzled source (m173): phys slot s8 of row l8 holds chunk s8^l8.
  const int l8 = lane >> 3, s8 = lane & 7;
  const _Float16* bsrc =
      Wh + (size_t)(bn0 + wid * 32 + l8) * 2048 + (s8 ^ l8) * 8;
  char* const bd0 = (char*)&Bs[0][0] + wid * 4096;
  char* const bd1 = (char*)&Bs[1][0] + wid * 4096;

  // A raw fp32: two halves x two named sets (static indexing only)
  f32x4 ah0A[4], ah1A[4], ah0B[4], ah1B[4];

#define CVT_H0(ARR, Q) do {                                                \
    f16x8 hv0, hv1;                                                        \
    _Pragma("unroll") for (int j = 0; j < 4; ++j) {                        \
      hv0[j] = (_Float16)ARR[0][j]; hv0[j + 4] = (_Float16)ARR[1][j];      \
      hv1[j] = (_Float16)ARR[2][j]; hv1[j + 4] = (_Float16)ARR[3][j];      \
    }                                                                      \
    *(f16x8*)((char*)&As[Q][0] + awc[0]) = hv0;                            \
    *(f16x8*)((char*)&As[Q][0] + awc[1]) = hv1;                            \
  } while (0)

#define CVT_H1(ARR, Q) do {                                                \
    f16x8 hv0, hv1;                                                        \
    _Pragma("unroll") for (int j = 0; j < 4; ++j) {                        \
      hv0[j] = (_Float16)ARR[0][j]; hv0[j + 4] = (_Float16)ARR[1][j];      \
      hv1[j] = (_Float16)ARR[2][j]; hv1[j + 4] = (_Float16)ARR[3][j];      \
    }                                                                      \
    *(f16x8*)((char*)&As[Q][0] + awc[2]) = hv0;                            \
    *(f16x8*)((char*)&As[Q][0] + awc[3]) = hv1;                            \
  } while (0)

#define FRAGS(P, KS, FA, FB) do {                                          \
    _Pragma("unroll") for (int mf = 0; mf < 4; ++mf) {                     \
      int row = wm * 64 + mf * 16 + lrow;                                  \
      int off = row * 128 + ((((KS)*4 + lq) ^ (row & 7)) << 4);            \
      FA[mf] = *(const f16x8*)((const char*)&As[P][0] + off);              \
    }                                                                      \
    _Pragma("unroll") for (int nf = 0; nf < 4; ++nf) {                     \
      int row = wn * 64 + nf * 16 + lrow;                                  \
      int off = row * 128 + ((((KS)*4 + lq) ^ (row & 7)) << 4);            \
      FB[nf] = *(const f16x8*)((const char*)&Bs[P][0] + off);              \
    }                                                                      \
  } while (0)

#define MFMA16(FA, FB) do {                                                \
    __builtin_amdgcn_s_setprio(1);                                         \
    _Pragma("unroll") for (int mf = 0; mf < 4; ++mf)                       \
      _Pragma("unroll") for (int nf = 0; nf < 4; ++nf)                     \
        acc[mf][nf] = __builtin_amdgcn_mfma_f32_16x16x32_f16(              \
            FA[mf], FB[nf], acc[mf][nf], 0, 0, 0);                         \
    __builtin_amdgcn_s_setprio(0);                                         \
  } while (0)

  // One K-step KT (P = KT&1, Q = other). Entry: As[P]=A(KT), Bs[P]=B(KT)
  // published; CVT-sets hold A(KT+1); outstanding VMEM = {A(KT+1) drained
  // by cvt deps... i.e. nothing older than this step's issues}.
#define STEP(KT, P, Q, H0L, H1L, H0C, H1C, BDQ) do {                       \
    const int kb_ = ((KT) + 1 > 31) ? 31 : (KT) + 1;                       \
    const int ka_ = ((KT) + 2 > 31) ? 31 : (KT) + 2;                       \
    { /* phase 0 */                                                        \
      f16x8 fa[4], fb[4];                                                  \
      FRAGS(P, 0, fa, fb);                                                 \
      _Pragma("unroll") for (int i = 0; i < 4; ++i)   /* B(KT+1) */        \
        GLD_LDS16(bsrc + (size_t)i * 8 * 2048 + (size_t)kb_ * 64,          \
                  (BDQ) + i * 1024);                                       \
      _Pragma("unroll") for (int c = 0; c < 4; ++c)   /* A(KT+2).h0 */     \
        H0L[c] = *(const f32x4*)(xsrc + (size_t)ka_ * 64 + c * 4);         \
      CVT_H0(H0C, Q);                                  /* A(KT+1).h0 */    \
      __builtin_amdgcn_s_barrier();                                        \
      asm volatile("s_waitcnt lgkmcnt(0)" ::: "memory");                   \
      __builtin_amdgcn_sched_barrier(0);                                   \
      MFMA16(fa, fb);                                                      \
      __builtin_amdgcn_s_barrier();                                        \
    }                                                                      \
    { /* phase 1 */                                                        \
      f16x8 fa[4], fb[4];                                                  \
      FRAGS(P, 1, fa, fb);                                                 \
      _Pragma("unroll") for (int c = 0; c < 4; ++c)   /* A(KT+2).h1 */     \
        H1L[c] = *(const f32x4*)(xsrc + (size_t)ka_ * 64 + 16 + c * 4);    \
      CVT_H1(H1C, Q);                                  /* A(KT+1).h1 */    \
      asm volatile("s_waitcnt vmcnt(8) lgkmcnt(0)" ::: "memory");          \
      __builtin_amdgcn_sched_barrier(0);                                   \
      __builtin_amdgcn_s_barrier();                                        \
      MFMA16(fa, fb);                                                      \
      __builtin_amdgcn_s_barrier();                                        \
    }                                                                      \
  } while (0)

  // ---- prologue: B(0)->Bs[0]; A(0)->setA, cvt -> As[0]; A(1)->setB ----
#pragma unroll
  for (int i = 0; i < 4; ++i)
    GLD_LDS16(bsrc + (size_t)i * 8 * 2048, bd0 + i * 1024);
#pragma unroll
  for (int c = 0; c < 4; ++c) ah0A[c] = *(const f32x4*)(xsrc + c * 4);
#pragma unroll
  for (int c = 0; c < 4; ++c) ah1A[c] = *(const f32x4*)(xsrc + 16 + c * 4);
#pragma unroll
  for (int c = 0; c < 4; ++c) ah0B[c] = *(const f32x4*)(xsrc + 64 + c * 4);
#pragma unroll
  for (int c = 0; c < 4; ++c) ah1B[c] = *(const f32x4*)(xsrc + 80 + c * 4);
  CVT_H0(ah0A, 0);  // compiler waits A(0) deps; B(0)+A(0) older -> drained
  CVT_H1(ah1A, 0);
  asm volatile("s_waitcnt lgkmcnt(0)" ::: "memory");
  __builtin_amdgcn_s_barrier();
  // entry: setB = A(1); outstanding = {A(1)... already drained? no: A(1)
  // loads are younger than A(0); cvt waits drained through A(0) only ->
  // A(1) (8 ops) may remain in flight. Step 0 P1's vmcnt(8) accounts:
  // outstanding there = A(1)leftover(<=8 drained by cvt deps at step 0)
  // + B(1):4 + A(2):8. The cvt of A(1) in step 0 forces its drain first
  // (register deps), so at the P1 wait only {B(1):4, A(2):8} remain ->
  // vmcnt(8) drains B(1). Invariant holds inductively.

  for (int kt = 0; kt < 32; kt += 2) {
    STEP(kt, 0, 1, ah0A, ah1A, ah0B, ah1B, bd1);      // consume tile kt
    STEP(kt + 1, 1, 0, ah0B, ah1B, ah0A, ah1A, bd0);  // consume kt+1
  }
#undef STEP
#undef MFMA16
#undef FRAGS
#undef CVT_H0
#undef CVT_H1

  // ---- epilogue: softplus-difference partial for this N-quarter ----
  // acc[mf][nf][r]: row = bm0 + wm*64 + mf*16 + lq*4 + r
  //                 col = bn0 + wn*64 + nf*16 + lrow
  float dpart[16];
#pragma unroll
  for (int i = 0; i < 16; ++i) dpart[i] = 0.f;
#pragma unroll
  for (int nf = 0; nf < 4; ++nf) {
    int h = bn0 + wn * 64 + nf * 16 + lrow;
    float hbv = hb[h];
    float u0 = U[2 * h], u1 = U[2 * h + 1];
#pragma unroll
    for (int mf = 0; mf < 4; ++mf)
#pragma unroll
      for (int r = 0; r < 4; ++r) {
        float pf = acc[mf][nf][r] + hbv;
        dpart[mf * 4 + r] += softplus_f(pf + u0) - softplus_f(pf + u1);
      }
  }
#pragma unroll
  for (int i = 0; i < 16; ++i) {
    float v = dpart[i];
    v += __shfl_xor(v, 1);
    v += __shfl_xor(v, 2);
    v += __shfl_xor(v, 4);
    v += __shfl_xor(v, 8);
    dpart[i] = v;
  }
  if (lrow == 0) {
#pragma unroll
    for (int mf = 0; mf < 4; ++mf)
#pragma unroll
      for (int r = 0; r < 4; ++r)
        atomicAdd(&sD[wm * 64 + mf * 16 + lq * 4 + r], dpart[mf * 4 + r]);
  }
  __syncthreads();
  if (t < 128) Dp[nq * 16384 + bm0 + t] = sD[t];
}

// ---- combine the four N-quarter partials + sigmoid ----
__global__ __launch_bounds__(256) void k_final(const float* __restrict__ Dp,
                                               const float* __restrict__ yb,
                                               float* __restrict__ out) {
  int i = blockIdx.x * 256 + threadIdx.x;  // 0..16383
  float D = Dp[i] + Dp[16384 + i] + Dp[2 * 16384 + i] + Dp[3 * 16384 + i] +
            yb[0] - yb[1];  // logit0 - logit1
  float e = __expf(-D);
  float o0 = 1.f / (1.f + e);
  float o1 = e * o0;
  *(float2*)(out + (size_t)i * 2) = make_float2(o0, o1);
}

extern "C" void kernel_launch(void* const* d_in, const int* in_sizes, int n_in,
                              void* d_out, int out_size, void* d_ws,
                              size_t ws_size, hipStream_t stream) {
  const float* X = (const float*)d_in[0];
  const float* W = (const float*)d_in[1];
  const float* U = (const float*)d_in[2];
  const float* hb = (const float*)d_in[3];
  const float* yb = (const float*)d_in[4];
  float* out = (float*)d_out;
  _Float16* Wh = (_Float16*)d_ws;                       // 2 MB
  float* Dp = (float*)((char*)d_ws + 2 * 1024 * 1024);  // 256 KB partials

  hipLaunchKernelGGL(k_cvt_w, dim3(512), dim3(256), 0, stream, W, Wh);
  hipLaunchKernelGGL(k_main, dim3(512), dim3(256), 0, stream, X, Wh, U, hb,
                     Dp);
  hipLaunchKernelGGL(k_final, dim3(64), dim3(256), 0, stream, Dp, yb, out);
}

// Round 18
// 61.179 us; speedup vs baseline: 1.5864x; 1.5864x over previous
//
#include <hip/hip_runtime.h>
#include <hip/hip_bf16.h>
#include <hip/hip_fp16.h>
#include <stdint.h>

typedef __attribute__((ext_vector_type(8))) _Float16 f16x8;
typedef __attribute__((ext_vector_type(4))) float f32x4;
typedef __attribute__((ext_vector_type(4))) int i32x4;

#define GLD_LDS16(g, l) __builtin_amdgcn_global_load_lds( \
    (const __attribute__((address_space(1))) uint32_t*)(g), \
    (__attribute__((address_space(3))) uint32_t*)(l), 16, 0, 0)

// ---------------- W fp32 -> fp16 (into workspace), 512x2048 -------------
__global__ __launch_bounds__(256) void k_cvt_w(const float* __restrict__ W,
                                               _Float16* __restrict__ Wh) {
  int i = (blockIdx.x * 256 + threadIdx.x) * 8;  // 1048576 elems total
  float4 a = *(const float4*)(W + i);
  float4 b = *(const float4*)(W + i + 4);
  union { _Float16 h[8]; i32x4 v; } u;
  u.h[0] = (_Float16)a.x; u.h[1] = (_Float16)a.y;
  u.h[2] = (_Float16)a.z; u.h[3] = (_Float16)a.w;
  u.h[4] = (_Float16)b.x; u.h[5] = (_Float16)b.y;
  u.h[6] = (_Float16)b.z; u.h[7] = (_Float16)b.w;
  *(i32x4*)(Wh + i) = u.v;
}

__device__ inline float softplus_f(float x) {
  float e = __expf(-fabsf(x));
  return fmaxf(x, 0.f) + __logf(1.f + e);
}

// ---- fused GEMM(fp16 MFMA) + softplus-diff: UNPINNED 2-BARRIER PHASES ----
// Geometry = R15 (proven): block 128x256 (N-split 2), BK=64, 32 K-steps,
// 8 waves 2Mx4N, wave 64x64, XCD pairing (FETCH 74MB), zero-conflict
// swizzles, absmax 0.0156 numerics.
// R18 deltas (wait-redundancy analysis):
//  - NO explicit vmcnt: cvt A(t+1)'s compiler-counted vmcnt(8) transitively
//    drains the older B(t+1) DMA (vmcnt is ordered). Never drains to 0.
//  - NO sched_barrier, NO post-barrier lgkm drain: frag reads are IR loads;
//    compiler interleaves counted lgkmcnt with MFMA (m97 evidence).
//  - 2 barriers/step (was 4): per phase {frag reads; stage issue;
//    [P1: A loads + cvt/write]; lgkmcnt(0) (drain own reads + publish own
//    writes); s_barrier; MFMA}. Race-checked: any wave past barrier k
//    implies all waves drained their reads before barrier k.
__global__ __launch_bounds__(512, 2) void k_main(
    const float* __restrict__ X,      // [16384][2048]
    const _Float16* __restrict__ Wh,  // [512][2048]
    const float* __restrict__ U,      // [512][2]
    const float* __restrict__ hb,     // [512]
    float* __restrict__ Dp) {         // [2][16384] partial logit-diffs
  __shared__ __align__(16) _Float16 As[2][128 * 64];  // 2 x 16 KB
  __shared__ __align__(16) _Float16 Bs[3][256 * 64];  // 3 x 32 KB
  __shared__ float sD[128];

  const int t = threadIdx.x;
  const int lane = t & 63;
  const int wid = t >> 6;   // 0..7
  const int wm = wid >> 2;  // 0..1 (M half)
  const int wn = wid & 3;   // 0..3 (N quarter)
  const int bx = blockIdx.x;
  const int rt = (bx >> 4) * 8 + (bx & 7);  // row-tile 0..127
  const int nhalf = (bx >> 3) & 1;          // pair partner bx^8: same XCD
  const int bm0 = rt * 128;
  const int bn0 = nhalf * 256;
  const int lrow = lane & 15, lq = lane >> 4;

  if (t < 128) sD[t] = 0.f;

  f32x4 acc[4][4];
#pragma unroll
  for (int m = 0; m < 4; ++m)
#pragma unroll
    for (int n = 0; n < 4; ++n) acc[m][n] = (f32x4){0.f, 0.f, 0.f, 0.f};

  // A staging: thread -> row t>>2 (0..127), k-chunk16 t&3 (proven swizzle).
  const int arow = t >> 2, ach = t & 3;
  const float* xsrc = X + (size_t)(bm0 + arow) * 2048 + ach * 16;
  const int c0 = ach * 2;
  const int aw0 = arow * 128 + (((c0) ^ (arow & 7)) << 4);
  const int aw1 = arow * 128 + (((c0 + 1) ^ (arow & 7)) << 4);

  // B staging: wave wid rows [wid*32,+32), 4 gld_lds of 1KB, pre-swizzled
  // source (m173): phys slot s8 of row l8 holds chunk s8^l8.
  const int l8 = lane >> 3, s8 = lane & 7;
  const _Float16* bsrc =
      Wh + (size_t)(bn0 + wid * 32 + l8) * 2048 + (s8 ^ l8) * 8;
  char* const bd0 = (char*)&Bs[0][0] + wid * 4096;
  char* const bd1 = (char*)&Bs[1][0] + wid * 4096;
  char* const bd2 = (char*)&Bs[2][0] + wid * 4096;

  f32x4 arA[4], arB[4];  // A fp32 raw, two named sets (static idx only)

#define CVT_WRITE_A(ARC, Q) do {                                           \
    f16x8 hv0, hv1;                                                        \
    _Pragma("unroll") for (int j = 0; j < 4; ++j) {                        \
      hv0[j] = (_Float16)ARC[0][j]; hv0[j + 4] = (_Float16)ARC[1][j];      \
      hv1[j] = (_Float16)ARC[2][j]; hv1[j + 4] = (_Float16)ARC[3][j];      \
    }                                                                      \
    *(f16x8*)((char*)&As[Q][0] + aw0) = hv0;                               \
    *(f16x8*)((char*)&As[Q][0] + aw1) = hv1;                               \
  } while (0)

#define FRAGS(P, BR, KS, FA, FB) do {                                      \
    _Pragma("unroll") for (int mf = 0; mf < 4; ++mf) {                     \
      int row = wm * 64 + mf * 16 + lrow;                                  \
      int off = row * 128 + ((((KS)*4 + lq) ^ (row & 7)) << 4);            \
      FA[mf] = *(const f16x8*)((const char*)&As[P][0] + off);              \
    }                                                                      \
    _Pragma("unroll") for (int nf = 0; nf < 4; ++nf) {                     \
      int row = wn * 64 + nf * 16 + lrow;                                  \
      int off = row * 128 + ((((KS)*4 + lq) ^ (row & 7)) << 4);            \
      FB[nf] = *(const f16x8*)((const char*)&Bs[BR][0] + off);             \
    }                                                                      \
  } while (0)

#define MFMA16(FA, FB) do {                                                \
    __builtin_amdgcn_s_setprio(1);                                         \
    _Pragma("unroll") for (int mf = 0; mf < 4; ++mf)                       \
      _Pragma("unroll") for (int nf = 0; nf < 4; ++nf)                     \
        acc[mf][nf] = __builtin_amdgcn_mfma_f32_16x16x32_f16(              \
            FA[mf], FB[nf], acc[mf][nf], 0, 0, 0);                         \
    __builtin_amdgcn_s_setprio(0);                                         \
  } while (0)

  // One K-step (KT). Entry: As[P]=A(KT), Bs[BR]=B(KT) published; ARC holds
  // A(KT+1); outstanding VMEM = {B(KT+1):4, A(KT+1): drained by this
  // step's cvt deps}.
#define STEP(KT, P, Q, ARL, ARC, BR, BWD) do {                             \
    const int kb_ = ((KT) + 2 > 31) ? 31 : (KT) + 2;                       \
    { /* ---- phase 0: frags ks0 (pre-barrier) + B(t+2) DMA ---- */        \
      f16x8 fa[4], fb[4];                                                  \
      FRAGS(P, BR, 0, fa, fb);                                             \
      _Pragma("unroll") for (int i = 0; i < 4; ++i)                        \
        GLD_LDS16(bsrc + (size_t)i * 16384 + (size_t)kb_ * 64,             \
                  (BWD) + i * 1024);                                       \
      asm volatile("s_waitcnt lgkmcnt(0)" ::: "memory");                   \
      __builtin_amdgcn_s_barrier();                                        \
      MFMA16(fa, fb);                                                      \
    }                                                                      \
    { /* ---- phase 1: frags ks1 + A(t+2) loads + cvt A(t+1) ---- */       \
      f16x8 fa[4], fb[4];                                                  \
      FRAGS(P, BR, 1, fa, fb);                                             \
      _Pragma("unroll") for (int c = 0; c < 4; ++c)                        \
        ARL[c] = *(const f32x4*)(xsrc + (size_t)kb_ * 64 + c * 4);         \
      CVT_WRITE_A(ARC, Q); /* implicit vmcnt(8): drains B(t+1) too */      \
      asm volatile("s_waitcnt lgkmcnt(0)" ::: "memory");                   \
      __builtin_amdgcn_s_barrier();                                        \
      MFMA16(fa, fb);                                                      \
    }                                                                      \
  } while (0)

  // ---- prologue: B(0)->s0, B(1)->s1, A(0)->arA, A(1)->arB;
  //      cvt A(0)->As[0] (implicit vmcnt(4) drains B0,B1,A0) ----
#pragma unroll
  for (int i = 0; i < 4; ++i)
    GLD_LDS16(bsrc + (size_t)i * 16384, bd0 + i * 1024);
#pragma unroll
  for (int i = 0; i < 4; ++i)
    GLD_LDS16(bsrc + (size_t)i * 16384 + 64, bd1 + i * 1024);
#pragma unroll
  for (int c = 0; c < 4; ++c) arA[c] = *(const f32x4*)(xsrc + c * 4);
#pragma unroll
  for (int c = 0; c < 4; ++c) arB[c] = *(const f32x4*)(xsrc + 64 + c * 4);
  CVT_WRITE_A(arA, 0);
  asm volatile("s_waitcnt vmcnt(4) lgkmcnt(0)" ::: "memory");
  __builtin_amdgcn_s_barrier();
  // entry: outstanding = {A(1):4}; As[0], Bs[0..1] staged+published.

  // period-6 (A parity x B mod-3); 30 steps unrolled + 2 peeled
  for (int kt = 0; kt < 30; kt += 6) {
    STEP(kt + 0, 0, 1, arA, arB, 0, bd2);
    STEP(kt + 1, 1, 0, arB, arA, 1, bd0);
    STEP(kt + 2, 0, 1, arA, arB, 2, bd1);
    STEP(kt + 3, 1, 0, arB, arA, 0, bd2);
    STEP(kt + 4, 0, 1, arA, arB, 1, bd0);
    STEP(kt + 5, 1, 0, arB, arA, 2, bd1);
  }
  STEP(30, 0, 1, arA, arB, 0, bd2);  // dup prefetches land in dead slots
  STEP(31, 1, 0, arB, arA, 1, bd0);
#undef STEP
#undef MFMA16
#undef FRAGS
#undef CVT_WRITE_A

  // ---- epilogue: softplus-difference partial for this N-half ----
  // acc[mf][nf][r]: row = bm0 + wm*64 + mf*16 + lq*4 + r
  //                 col = bn0 + wn*64 + nf*16 + lrow
  float dpart[16];
#pragma unroll
  for (int i = 0; i < 16; ++i) dpart[i] = 0.f;
#pragma unroll
  for (int nf = 0; nf < 4; ++nf) {
    int h = bn0 + wn * 64 + nf * 16 + lrow;
    float hbv = hb[h];
    float u0 = U[2 * h], u1 = U[2 * h + 1];
#pragma unroll
    for (int mf = 0; mf < 4; ++mf)
#pragma unroll
      for (int r = 0; r < 4; ++r) {
        float pf = acc[mf][nf][r] + hbv;
        dpart[mf * 4 + r] += softplus_f(pf + u0) - softplus_f(pf + u1);
      }
  }
#pragma unroll
  for (int i = 0; i < 16; ++i) {
    float v = dpart[i];
    v += __shfl_xor(v, 1);
    v += __shfl_xor(v, 2);
    v += __shfl_xor(v, 4);
    v += __shfl_xor(v, 8);
    dpart[i] = v;
  }
  if (lrow == 0) {
#pragma unroll
    for (int mf = 0; mf < 4; ++mf)
#pragma unroll
      for (int r = 0; r < 4; ++r)
        atomicAdd(&sD[wm * 64 + mf * 16 + lq * 4 + r], dpart[mf * 4 + r]);
  }
  __syncthreads();
  if (t < 128) Dp[nhalf * 16384 + bm0 + t] = sD[t];
}

// ---- combine the two N-half partials + sigmoid ----
__global__ __launch_bounds__(256) void k_final(const float* __restrict__ Dp,
                                               const float* __restrict__ yb,
                                               float* __restrict__ out) {
  int i = blockIdx.x * 256 + threadIdx.x;  // 0..16383
  float D = Dp[i] + Dp[16384 + i] + yb[0] - yb[1];  // logit0 - logit1
  float e = __expf(-D);
  float o0 = 1.f / (1.f + e);
  float o1 = e * o0;
  *(float2*)(out + (size_t)i * 2) = make_float2(o0, o1);
}

extern "C" void kernel_launch(void* const* d_in, const int* in_sizes, int n_in,
                              void* d_out, int out_size, void* d_ws,
                              size_t ws_size, hipStream_t stream) {
  const float* X = (const float*)d_in[0];
  const float* W = (const float*)d_in[1];
  const float* U = (const float*)d_in[2];
  const float* hb = (const float*)d_in[3];
  const float* yb = (const float*)d_in[4];
  float* out = (float*)d_out;
  _Float16* Wh = (_Float16*)d_ws;                       // 2 MB
  float* Dp = (float*)((char*)d_ws + 2 * 1024 * 1024);  // 128 KB partials

  hipLaunchKernelGGL(k_cvt_w, dim3(512), dim3(256), 0, stream, W, Wh);
  hipLaunchKernelGGL(k_main, dim3(256), dim3(512), 0, stream, X, Wh, U, hb, Dp);
  hipLaunchKernelGGL(k_final, dim3(64), dim3(256), 0, stream, Dp, yb, out);
}